// Round 6
// baseline (329.808 us; speedup 1.0000x reference)
//
#include <hip/hip_runtime.h>
#include <cstdint>
#include <cstddef>

// ---------------------------------------------------------------------------
// MambaBlock on MI355X (gfx950).
// cast_multi -> G1(256sq 4-phase/tile pipelined, fused bf16 epilogue) ->
// conv(bf16) -> G2(K-split) -> reduce -> G3(softplus) -> scan(A,B,C) ->
// G4(256sq split-K x4) -> reduce4+bias
// ---------------------------------------------------------------------------

typedef __bf16 bf16x8 __attribute__((ext_vector_type(8)));
typedef float f32x4 __attribute__((ext_vector_type(4)));

#define GLDS16(g, l)                                        \
  __builtin_amdgcn_global_load_lds(                         \
      (__attribute__((address_space(1))) void*)(g),         \
      (__attribute__((address_space(3))) void*)(l), 16, 0, 0)

#define FENCE() asm volatile("" ::: "memory")
#define BARRIER()                      \
  do {                                 \
    FENCE();                           \
    __builtin_amdgcn_s_barrier();      \
    FENCE();                           \
  } while (0)

static __device__ __forceinline__ unsigned short f2b(float f) {
  unsigned int x = __builtin_bit_cast(unsigned int, f);
  x += 0x7fffu + ((x >> 16) & 1u);
  return (unsigned short)(x >> 16);
}

static __device__ __forceinline__ float b2f(unsigned short u) {
  return __builtin_bit_cast(float, (unsigned int)u << 16);
}

static __device__ __forceinline__ float sigmoidf_fast(float x) {
  return 1.0f / (1.0f + __expf(-x));
}

// ---------------- merged cast fp32 -> bf16 (5 segments, one launch) --------
struct CastArgs {
  const float* src[5];
  unsigned short* dst[5];
  int n4[5];
};

__global__ __launch_bounds__(256) void cast_multi(CastArgs a) {
  const int stride = gridDim.x * 256;
  const int t = blockIdx.x * 256 + threadIdx.x;
#pragma unroll
  for (int k = 0; k < 5; ++k) {
    const float4* src = reinterpret_cast<const float4*>(a.src[k]);
    ushort4* dst = reinterpret_cast<ushort4*>(a.dst[k]);
    const int n4 = a.n4[k];
    for (int i = t; i < n4; i += stride) {
      float4 v = src[i];
      ushort4 o;
      o.x = f2b(v.x); o.y = f2b(v.y); o.z = f2b(v.z); o.w = f2b(v.w);
      dst[i] = o;
    }
  }
}

// ---------------- 256x256 tile, BK=64, 8 waves, 4-phase/tile pipeline ------
// Gray-code quadrant phases (mh,nh): (0,0),(1,0),(1,1),(0,1); per wave the
// 128x64 output is split across both A-halves (rows wr*64 & 128+wr*64) and
// both B-halves (cols wc*32 & 128+wc*32), so each phase consumes exactly one
// A-half x one B-half.  One half-tile staged per phase into the slot that
// died last phase.  Waits: vmcnt(6)@p1, vmcnt(4)@p3 (cover loads >=3 phases
// old; every ds_read covered by a wait at an earlier phase + barrier).
// MODE 1: partial[ks][M][N] (ks=blockIdx.z).  MODE 2: G1 fused bf16 epilogue.
template <int MODE>
__global__ __launch_bounds__(512) void gemm256_bt(
    const unsigned short* __restrict__ A, const unsigned short* __restrict__ B,
    float* __restrict__ Cp, unsigned short* __restrict__ xib,
    unsigned short* __restrict__ rsb, const float* __restrict__ bias,
    int M, int N, int K, int Kslice) {
  // [buf:2][A0|A1|B0|B1][128][64] bf16 ; 4 x 16KB per buf = 128KB total
  __shared__ __align__(16) unsigned short lds[65536];
  const int tid = threadIdx.x;
  const int l = tid & 63;
  const int w = tid >> 6;       // 0..7
  const int wr = w >> 2;        // 0..1
  const int wc = w & 3;         // 0..3

  // T1: bijective XCD swizzle (nwg % 8 == 0 in all uses)
  const int nwg = gridDim.x * gridDim.y;
  const int q = nwg >> 3;
  int flat = blockIdx.x + gridDim.x * blockIdx.y;
  flat = (flat & 7) * q + (flat >> 3);
  const int bx = flat % gridDim.x;
  const int by = flat / gridDim.x;

  const long brow = (long)bx * 256;
  const long bcol = (long)by * 256;
  const int ks = blockIdx.z;
  const int NT = Kslice >> 6;

  f32x4 acc[8][4] = {};

  const unsigned short* Ab = A + (size_t)brow * K + (size_t)ks * Kslice;
  const unsigned short* Bb = B + (size_t)bcol * K + (size_t)ks * Kslice;

  // half-tile staging: 128 rows x 64 k = 16KB; 512 thr x 2 x 16B loads.
  // LDS dest linear; global source pre-swizzled (slot ^= row&7, 8x16B slots).
  size_t soff[2];
  int doff[2];
#pragma unroll
  for (int i = 0; i < 2; ++i) {
    int idx = i * 512 + tid;      // 0..1023 -> row=idx>>3, phys slot=idx&7
    int r = idx >> 3, s = idx & 7;
    soff[i] = (size_t)r * K + (size_t)((s ^ (r & 7)) << 3);
    doff[i] = idx * 8;            // ushort offset
  }

  auto stA = [&](int kt, int mh) {
    const unsigned short* src = Ab + (size_t)(mh * 128) * K + (kt << 6);
    const int reg = (kt & 1) * 32768 + mh * 8192;
#pragma unroll
    for (int i = 0; i < 2; ++i) GLDS16(src + soff[i], &lds[reg + doff[i]]);
  };
  auto stB = [&](int kt, int nh) {
    const unsigned short* src = Bb + (size_t)(nh * 128) * K + (kt << 6);
    const int reg = (kt & 1) * 32768 + 16384 + nh * 8192;
#pragma unroll
    for (int i = 0; i < 2; ++i) GLDS16(src + soff[i], &lds[reg + doff[i]]);
  };

  // read side: swizzled slot = (hi + 4*kk) ^ (la&7)
  const int la = l & 15, hi = l >> 4;
  int swz[2];
  swz[0] = (hi ^ (la & 7)) * 8;
  swz[1] = ((hi + 4) ^ (la & 7)) * 8;
  int rowAoff[4], rowBoff[2];
#pragma unroll
  for (int qq = 0; qq < 4; ++qq) rowAoff[qq] = (wr * 64 + qq * 16 + la) * 64;
#pragma unroll
  for (int jj = 0; jj < 2; ++jj) rowBoff[jj] = (wc * 32 + jj * 16 + la) * 64;

  bf16x8 afr[4][2], bfr[2][2];

  auto readA = [&](int kt, int mh) {
    const int base = (kt & 1) * 32768 + mh * 8192;
#pragma unroll
    for (int qq = 0; qq < 4; ++qq)
#pragma unroll
      for (int kk = 0; kk < 2; ++kk)
        afr[qq][kk] = *reinterpret_cast<const bf16x8*>(&lds[base + rowAoff[qq] + swz[kk]]);
  };
  auto readB = [&](int kt, int nh) {
    const int base = (kt & 1) * 32768 + 16384 + nh * 8192;
#pragma unroll
    for (int jj = 0; jj < 2; ++jj)
#pragma unroll
      for (int kk = 0; kk < 2; ++kk)
        bfr[jj][kk] = *reinterpret_cast<const bf16x8*>(&lds[base + rowBoff[jj] + swz[kk]]);
  };

  auto mmaQ = [&](int mh, int nh) {
    __builtin_amdgcn_s_setprio(1);
#pragma unroll
    for (int qq = 0; qq < 4; ++qq)
#pragma unroll
      for (int jj = 0; jj < 2; ++jj)
#pragma unroll
        for (int kk = 0; kk < 2; ++kk)
          acc[mh * 4 + qq][nh * 2 + jj] = __builtin_amdgcn_mfma_f32_16x16x32_bf16(
              afr[qq][kk], bfr[jj][kk], acc[mh * 4 + qq][nh * 2 + jj], 0, 0, 0);
    __builtin_amdgcn_s_setprio(0);
  };

  // prologue: Ah0(0),Bh0(0),Ah1(0),Bh1(0),Bh0(1),Ah1(1); land first two.
  stA(0, 0); stB(0, 0); stA(0, 1); stB(0, 1); stB(1, 0); stA(1, 1);
  asm volatile("s_waitcnt vmcnt(8)" ::: "memory");
  BARRIER();

  for (int kt = 0; kt < NT; ++kt) {
    const bool tail = (kt >= NT - 2);
    // ---- p0: (mh0, nh0); stage Ah0(kt+1) ----
    if (kt + 1 < NT) stA(kt + 1, 0);
    readA(kt, 0); readB(kt, 0);
    BARRIER();
    asm volatile("s_waitcnt lgkmcnt(0)" ::: "memory");
    __builtin_amdgcn_sched_barrier(0);
    mmaQ(0, 0);
    BARRIER();
    // ---- p1: (mh1, nh0); stage Bh1(kt+1) ----
    if (tail) asm volatile("s_waitcnt vmcnt(0)" ::: "memory");
    else      asm volatile("s_waitcnt vmcnt(6)" ::: "memory");
    if (kt + 1 < NT) stB(kt + 1, 1);
    readA(kt, 1);
    BARRIER();
    asm volatile("s_waitcnt lgkmcnt(0)" ::: "memory");
    __builtin_amdgcn_sched_barrier(0);
    mmaQ(1, 0);
    BARRIER();
    // ---- p2: (mh1, nh1); stage Bh0(kt+2) ----
    if (kt + 2 < NT) stB(kt + 2, 0);
    readB(kt, 1);
    BARRIER();
    asm volatile("s_waitcnt lgkmcnt(0)" ::: "memory");
    __builtin_amdgcn_sched_barrier(0);
    mmaQ(1, 1);
    BARRIER();
    // ---- p3: (mh0, nh1); stage Ah1(kt+2) ----
    if (tail) asm volatile("s_waitcnt vmcnt(0)" ::: "memory");
    else      asm volatile("s_waitcnt vmcnt(4)" ::: "memory");
    if (kt + 2 < NT) stA(kt + 2, 1);
    readA(kt, 0);
    BARRIER();
    asm volatile("s_waitcnt lgkmcnt(0)" ::: "memory");
    __builtin_amdgcn_sched_barrier(0);
    mmaQ(0, 1);
    BARRIER();
  }

  // epilogue: row = brow + (m>>2)*128 + wr*64 + (m&3)*16 + (l>>4)*4 + r
  //           col = bcol + (n>>1)*128 + wc*32 + (n&1)*16 + (l&15)
  const long rbase = brow + wr * 64 + (l >> 4) * 4;
  const long cbase = bcol + wc * 32 + (l & 15);
  if (MODE == 1) {
    float* Cb = Cp + (size_t)ks * M * N;
#pragma unroll
    for (int m = 0; m < 8; ++m) {
      const long r0 = rbase + (m >> 2) * 128 + (m & 3) * 16;
#pragma unroll
      for (int n = 0; n < 4; ++n) {
        const long col = cbase + (n >> 1) * 128 + (n & 1) * 16;
#pragma unroll
        for (int r = 0; r < 4; ++r)
          Cb[(r0 + r) * (long)N + col] = acc[m][n][r];
      }
    }
  } else {
#pragma unroll
    for (int m = 0; m < 8; ++m) {
      const long r0 = rbase + (m >> 2) * 128 + (m & 3) * 16;
#pragma unroll
      for (int n = 0; n < 4; ++n) {
        const long col = cbase + (n >> 1) * 128 + (n & 1) * 16;
        const float bv = bias[col];
        const bool isres = col >= 4096;
        const long cc = isres ? col - 4096 : col;
#pragma unroll
        for (int r = 0; r < 4; ++r) {
          float v = acc[m][n][r] + bv;
          if (isres) {
            float s = v * sigmoidf_fast(v);
            rsb[(r0 + r) * 4096 + cc] = f2b(s);
          } else {
            xib[(r0 + r) * 4096 + cc] = f2b(v);
          }
        }
      }
    }
  }
}

// out = sum_{ks<4} part[ks] + bias (bias periodic with N=2048)
__global__ __launch_bounds__(256) void reduce4_bias(
    const float* __restrict__ part, const float* __restrict__ bias,
    float* __restrict__ out, int n4) {
  int stride = gridDim.x * 256;
  for (int f = blockIdx.x * 256 + threadIdx.x; f < n4; f += stride) {
    float4 s0 = reinterpret_cast<const float4*>(part)[f];
    float4 s1 = reinterpret_cast<const float4*>(part + 4194304ull)[f];
    float4 s2 = reinterpret_cast<const float4*>(part + 8388608ull)[f];
    float4 s3 = reinterpret_cast<const float4*>(part + 12582912ull)[f];
    float4 bv = reinterpret_cast<const float4*>(bias)[f & 511];
    float4 o;
    o.x = s0.x + s1.x + s2.x + s3.x + bv.x;
    o.y = s0.y + s1.y + s2.y + s3.y + bv.y;
    o.z = s0.z + s1.z + s2.z + s3.z + bv.z;
    o.w = s0.w + s1.w + s2.w + s3.w + bv.w;
    reinterpret_cast<float4*>(out)[f] = o;
  }
}

// ---------------- G3: softplus GEMM (m97 structure, 128x128) ----------------
__global__ __launch_bounds__(256) void gemm_bt_sp(
    const unsigned short* __restrict__ A, const unsigned short* __restrict__ B,
    float* __restrict__ C, int M, int N, int K) {
  __shared__ __align__(16) unsigned short lA[128 * 32];
  __shared__ __align__(16) unsigned short lB[128 * 32];
  const int tid = threadIdx.x;
  const int l = tid & 63;
  const int w = tid >> 6;
  const int wr = w >> 1, wc = w & 1;
  const long brow = (long)blockIdx.x * 128;
  const long bcol = (long)blockIdx.y * 128;

  f32x4 acc[4][4] = {};

  const int srow = tid >> 2;
  const int scol = (tid & 3) * 8;

  const unsigned short* Ab = A + (size_t)brow * K;
  const unsigned short* Bb = B + (size_t)bcol * K;

  for (int k0 = 0; k0 < K; k0 += 32) {
#pragma unroll
    for (int j = 0; j < 2; ++j) {
      GLDS16(Ab + (size_t)(j * 64 + srow) * K + k0 + scol, &lA[j * 2048 + tid * 8]);
      GLDS16(Bb + (size_t)(j * 64 + srow) * K + k0 + scol, &lB[j * 2048 + tid * 8]);
    }
    __syncthreads();
    bf16x8 af[4], bfr[4];
#pragma unroll
    for (int mt = 0; mt < 4; ++mt)
      af[mt] = *reinterpret_cast<const bf16x8*>(
          &lA[(wr * 64 + mt * 16 + (l & 15)) * 32 + (l >> 4) * 8]);
#pragma unroll
    for (int nt = 0; nt < 4; ++nt)
      bfr[nt] = *reinterpret_cast<const bf16x8*>(
          &lB[(wc * 64 + nt * 16 + (l & 15)) * 32 + (l >> 4) * 8]);
#pragma unroll
    for (int mt = 0; mt < 4; ++mt)
#pragma unroll
      for (int nt = 0; nt < 4; ++nt)
        acc[mt][nt] = __builtin_amdgcn_mfma_f32_16x16x32_bf16(
            af[mt], bfr[nt], acc[mt][nt], 0, 0, 0);
    __syncthreads();
  }

  const long r0 = brow + wr * 64 + ((l >> 4) * 4);
  const long c0 = bcol + wc * 64 + (l & 15);
#pragma unroll
  for (int mt = 0; mt < 4; ++mt) {
#pragma unroll
    for (int nt = 0; nt < 4; ++nt) {
      long col = c0 + nt * 16;
#pragma unroll
      for (int r = 0; r < 4; ++r) {
        long row = r0 + mt * 16 + r;
        float v = acc[mt][nt][r];
        v = (v > 20.0f) ? v : log1pf(__expf(v));
        C[row * (long)N + col] = v;
      }
    }
  }
}

// ---------------- depthwise causal conv1d (k=4) + SiLU, bf16 in/out --------
__global__ __launch_bounds__(256) void conv_silu_k(
    const unsigned short* __restrict__ xib, const float* __restrict__ cw,
    const float* __restrict__ cb, unsigned short* __restrict__ xcb) {
  const int d = blockIdx.x * 256 + threadIdx.x;  // 0..4095
  const int t0 = blockIdx.y * 128;
  const float4 wv = *reinterpret_cast<const float4*>(cw + (size_t)d * 4);
  const float bv = cb[d];
  float xm3 = (t0 >= 3) ? b2f(xib[(size_t)(t0 - 3) * 4096 + d]) : 0.0f;
  float xm2 = (t0 >= 2) ? b2f(xib[(size_t)(t0 - 2) * 4096 + d]) : 0.0f;
  float xm1 = (t0 >= 1) ? b2f(xib[(size_t)(t0 - 1) * 4096 + d]) : 0.0f;
  for (int tt = 0; tt < 128; ++tt) {
    const size_t t = (size_t)t0 + tt;
    float xt = b2f(xib[t * 4096 + d]);
    float a = bv + wv.x * xm3 + wv.y * xm2 + wv.z * xm1 + wv.w * xt;
    float s = a * sigmoidf_fast(a);
    xcb[t * 4096 + d] = f2b(s);
    xm3 = xm2; xm2 = xm1; xm1 = xt;
  }
}

// ---------------- G2: dbc partials, K-split x8 ----------------
__global__ __launch_bounds__(256) void gemm_dbc(
    const unsigned short* __restrict__ A, const unsigned short* __restrict__ B,
    float* __restrict__ part) {
  __shared__ __align__(16) unsigned short lA[64 * 32];
  __shared__ __align__(16) unsigned short lB[160 * 32];
  const int tid = threadIdx.x;
  const int l = tid & 63, w = tid >> 6;
  const int brow = blockIdx.x * 64;
  const int ks = blockIdx.y;
  const int K = 4096;
  f32x4 acc[10] = {};
  const int srow = tid >> 2, scol = (tid & 3) * 8;
  for (int k0 = ks * 512; k0 < ks * 512 + 512; k0 += 32) {
    GLDS16(A + (size_t)(brow + srow) * K + k0 + scol, &lA[tid * 8]);
#pragma unroll
    for (int j = 0; j < 3; ++j) {
      int li = j * 256 + tid;
      if (li < 640) {
        GLDS16(B + (size_t)(li >> 2) * K + k0 + (li & 3) * 8, &lB[li * 8]);
      }
    }
    __syncthreads();
    bf16x8 af = *reinterpret_cast<const bf16x8*>(
        &lA[(w * 16 + (l & 15)) * 32 + (l >> 4) * 8]);
#pragma unroll
    for (int nt = 0; nt < 10; ++nt) {
      bf16x8 bfr = *reinterpret_cast<const bf16x8*>(
          &lB[(nt * 16 + (l & 15)) * 32 + (l >> 4) * 8]);
      acc[nt] = __builtin_amdgcn_mfma_f32_16x16x32_bf16(af, bfr, acc[nt], 0, 0, 0);
    }
    __syncthreads();
  }
  const int r0 = brow + w * 16 + (l >> 4) * 4;
  const int c = l & 15;
#pragma unroll
  for (int nt = 0; nt < 10; ++nt)
#pragma unroll
    for (int r = 0; r < 4; ++r)
      part[((size_t)ks * 2048 + r0 + r) * 160 + nt * 16 + c] = acc[nt][r];
}

__global__ __launch_bounds__(256) void reduce_dbc(
    const float* __restrict__ part, unsigned short* __restrict__ drb,
    float* __restrict__ bc) {
  int idx = blockIdx.x * 256 + threadIdx.x;
  float s = 0.0f;
#pragma unroll
  for (int k = 0; k < 8; ++k) s += part[(size_t)k * 2048 * 160 + idx];
  int row = idx / 160, col = idx - row * 160;
  if (col < 128) drb[row * 128 + col] = f2b(s);
  else bc[row * 32 + (col - 128)] = s;
}

// ---------------- chunked selective scan (u from bf16) ----------------
__global__ __launch_bounds__(256) void scan_passA(
    const float* __restrict__ delta, const unsigned short* __restrict__ xcb,
    const float* __restrict__ bc, const float* __restrict__ alog,
    float* __restrict__ P, float* __restrict__ S) {
  __shared__ float lbc[1024];
  const int d = blockIdx.x * 256 + threadIdx.x;
  const int c = blockIdx.y;
  const int t0 = c * 32;
#pragma unroll
  for (int j = 0; j < 4; ++j) {
    int idx = j * 256 + threadIdx.x;
    lbc[idx] = bc[(size_t)t0 * 32 + idx];
  }
  __syncthreads();
  float a[16], h[16], p[16];
#pragma unroll
  for (int s = 0; s < 16; ++s) {
    a[s] = -__expf(alog[(size_t)d * 16 + s]);
    h[s] = 0.0f;
    p[s] = 1.0f;
  }
  for (int tt = 0; tt < 32; ++tt) {
    float dt = delta[(size_t)(t0 + tt) * 4096 + d];
    float u = b2f(xcb[(size_t)(t0 + tt) * 4096 + d]);
    float du = dt * u;
#pragma unroll
    for (int s = 0; s < 16; ++s) {
      float e = __expf(dt * a[s]);
      h[s] = e * h[s] + du * lbc[tt * 32 + s];
      p[s] *= e;
    }
  }
  size_t o = ((size_t)c * 4096 + d) * 16;
#pragma unroll
  for (int s = 0; s < 16; s += 4) {
    *reinterpret_cast<float4*>(&P[o + s]) = make_float4(p[s], p[s + 1], p[s + 2], p[s + 3]);
    *reinterpret_cast<float4*>(&S[o + s]) = make_float4(h[s], h[s + 1], h[s + 2], h[s + 3]);
  }
}

__global__ __launch_bounds__(256) void scan_passB(
    float* __restrict__ P, const float* __restrict__ S) {
  const int idx = blockIdx.x * 256 + threadIdx.x;
  float h = 0.0f;
  for (int c = 0; c < 64; ++c) {
    size_t o = (size_t)c * 65536 + idx;
    float p = P[o], sv = S[o];
    P[o] = h;
    h = p * h + sv;
  }
}

__global__ __launch_bounds__(256) void scan_passC(
    const float* __restrict__ delta, const unsigned short* __restrict__ xcb,
    const float* __restrict__ bc, const float* __restrict__ alog,
    const float* __restrict__ hst, const float* __restrict__ Dp,
    const unsigned short* __restrict__ rsb, unsigned short* __restrict__ yb) {
  __shared__ float lbc[1024];
  const int d = blockIdx.x * 256 + threadIdx.x;
  const int c = blockIdx.y;
  const int t0 = c * 32;
#pragma unroll
  for (int j = 0; j < 4; ++j) {
    int idx = j * 256 + threadIdx.x;
    lbc[idx] = bc[(size_t)t0 * 32 + idx];
  }
  __syncthreads();
  float a[16], h[16];
  size_t o = ((size_t)c * 4096 + d) * 16;
#pragma unroll
  for (int s = 0; s < 16; ++s) {
    a[s] = -__expf(alog[(size_t)d * 16 + s]);
    h[s] = hst[o + s];
  }
  const float Dv = Dp[d];
  for (int tt = 0; tt < 32; ++tt) {
    float dt = delta[(size_t)(t0 + tt) * 4096 + d];
    float u = b2f(xcb[(size_t)(t0 + tt) * 4096 + d]);
    float du = dt * u;
    float y = 0.0f;
#pragma unroll
    for (int s = 0; s < 16; ++s) {
      float e = __expf(dt * a[s]);
      h[s] = e * h[s] + du * lbc[tt * 32 + s];
      y += h[s] * lbc[tt * 32 + 16 + s];
    }
    float rs = b2f(rsb[(size_t)(t0 + tt) * 4096 + d]);  // silu(res), precomputed
    float v = (y + u * Dv) * rs;
    yb[(size_t)(t0 + tt) * 4096 + d] = f2b(v);
  }
}

// ---------------------------------------------------------------------------
extern "C" void kernel_launch(void* const* d_in, const int* in_sizes, int n_in,
                              void* d_out, int out_size, void* d_ws, size_t ws_size,
                              hipStream_t stream) {
  const float* x    = (const float*)d_in[0];
  const float* w1   = (const float*)d_in[1];
  const float* b1   = (const float*)d_in[2];
  const float* cw   = (const float*)d_in[3];
  const float* cb   = (const float*)d_in[4];
  const float* w2   = (const float*)d_in[5];
  const float* w3   = (const float*)d_in[6];
  const float* alog = (const float*)d_in[7];
  const float* Dp   = (const float*)d_in[8];
  const float* w4   = (const float*)d_in[9];
  const float* b4   = (const float*)d_in[10];
  float* out = (float*)d_out;

  char* ws = (char*)d_ws;
  size_t off = 0;
  auto alloc = [&](size_t b) {
    size_t o = off;
    off += (b + 255) & ~(size_t)255;
    return o;
  };
  unsigned short* w1b = (unsigned short*)(ws + alloc(2ull * 8192 * 2048));
  unsigned short* xb  = (unsigned short*)(ws + alloc(2ull * 2048 * 2048));
  unsigned short* w2b = (unsigned short*)(ws + alloc(2ull * 160 * 4096));
  unsigned short* w3b = (unsigned short*)(ws + alloc(2ull * 4096 * 128));
  unsigned short* w4b = (unsigned short*)(ws + alloc(2ull * 2048 * 4096));
  unsigned short* xib = (unsigned short*)(ws + alloc(2ull * 2048 * 4096));
  unsigned short* rsb = (unsigned short*)(ws + alloc(2ull * 2048 * 4096));
  unsigned short* xcb = (unsigned short*)(ws + alloc(2ull * 2048 * 4096));
  unsigned short* drb = (unsigned short*)(ws + alloc(2ull * 2048 * 128));
  float* bcb  = (float*)(ws + alloc(4ull * 2048 * 32));
  // delta(33.5MB) + P(16.8MB) + S(16.8MB) contiguous; exactly span the 67MB
  // G4 partial buffer.
  float* delta = (float*)(ws + alloc(4ull * 2048 * 4096));
  float* P = (float*)(ws + alloc(4ull * 64 * 4096 * 16));
  float* S = (float*)(ws + alloc(4ull * 64 * 4096 * 16));
  float* part  = delta;                 // G2 partials (10.5MB), consumed pre-G3
  unsigned short* yb = xib;             // xib dead after conv
  float* part4 = delta;                 // spans delta+P+S, all dead after scanC

  if (ws_size < off) return;

  CastArgs ca;
  ca.src[0] = w1; ca.dst[0] = w1b; ca.n4[0] = 8192 * 2048 / 4;
  ca.src[1] = x;  ca.dst[1] = xb;  ca.n4[1] = 2048 * 2048 / 4;
  ca.src[2] = w2; ca.dst[2] = w2b; ca.n4[2] = 160 * 4096 / 4;
  ca.src[3] = w3; ca.dst[3] = w3b; ca.n4[3] = 4096 * 128 / 4;
  ca.src[4] = w4; ca.dst[4] = w4b; ca.n4[4] = 2048 * 4096 / 4;
  cast_multi<<<2048, 256, 0, stream>>>(ca);

  // G1: (M=2048, N=8192, K=2048) -> xib (bf16), rsb = silu(res) (bf16)
  gemm256_bt<2><<<dim3(8, 32, 1), 512, 0, stream>>>(
      xb, w1b, nullptr, xib, rsb, b1, 2048, 8192, 2048, 2048);
  // conv + silu (bf16 in/out)
  conv_silu_k<<<dim3(16, 16), 256, 0, stream>>>(xib, cw, cb, xcb);
  // G2 + reduce
  gemm_dbc<<<dim3(32, 8), 256, 0, stream>>>(xcb, w2b, part);
  reduce_dbc<<<1280, 256, 0, stream>>>(part, drb, bcb);
  // G3: delta = softplus(dr @ delta_w^T)
  gemm_bt_sp<<<dim3(16, 32), 256, 0, stream>>>(drb, w3b, delta, 2048, 4096, 128);
  // scan
  scan_passA<<<dim3(16, 64), 256, 0, stream>>>(delta, xcb, bcb, alog, P, S);
  scan_passB<<<256, 256, 0, stream>>>(P, S);
  scan_passC<<<dim3(16, 64), 256, 0, stream>>>(delta, xcb, bcb, alog, P, Dp, rsb, yb);
  // G4: out = y @ out_w^T + b4   (M=2048, N=2048, K=4096) — split-K x4
  gemm256_bt<1><<<dim3(8, 8, 4), 512, 0, stream>>>(
      yb, w4b, part4, nullptr, nullptr, nullptr, 2048, 2048, 4096, 1024);
  reduce4_bias<<<1024, 256, 0, stream>>>(part4, b4, out, 2048 * 2048 / 4);
}

// Round 7
// 304.260 us; speedup vs baseline: 1.0840x; 1.0840x over previous
//
#include <hip/hip_runtime.h>
#include <cstdint>
#include <cstddef>

// ---------------------------------------------------------------------------
// MambaBlock on MI355X (gfx950).
// cast_multi -> G1(256sq pipelined, fused bf16 epilogue) -> conv(bf16) ->
// G2(K-split) -> reduce -> G3(softplus) -> scan(A,B,C) ->
// G4(128sq pipelined, full-K, fused bias)
// ---------------------------------------------------------------------------

typedef __bf16 bf16x8 __attribute__((ext_vector_type(8)));
typedef float f32x4 __attribute__((ext_vector_type(4)));

#define GLDS16(g, l)                                        \
  __builtin_amdgcn_global_load_lds(                         \
      (__attribute__((address_space(1))) void*)(g),         \
      (__attribute__((address_space(3))) void*)(l), 16, 0, 0)

#define FENCE() asm volatile("" ::: "memory")
#define BARRIER()                      \
  do {                                 \
    FENCE();                           \
    __builtin_amdgcn_s_barrier();      \
    FENCE();                           \
  } while (0)

static __device__ __forceinline__ unsigned short f2b(float f) {
  unsigned int x = __builtin_bit_cast(unsigned int, f);
  x += 0x7fffu + ((x >> 16) & 1u);
  return (unsigned short)(x >> 16);
}

static __device__ __forceinline__ float b2f(unsigned short u) {
  return __builtin_bit_cast(float, (unsigned int)u << 16);
}

static __device__ __forceinline__ float sigmoidf_fast(float x) {
  return 1.0f / (1.0f + __expf(-x));
}

// ---------------- merged cast fp32 -> bf16 (5 segments, one launch) --------
struct CastArgs {
  const float* src[5];
  unsigned short* dst[5];
  int n4[5];
};

__global__ __launch_bounds__(256) void cast_multi(CastArgs a) {
  const int stride = gridDim.x * 256;
  const int t = blockIdx.x * 256 + threadIdx.x;
#pragma unroll
  for (int k = 0; k < 5; ++k) {
    const float4* src = reinterpret_cast<const float4*>(a.src[k]);
    ushort4* dst = reinterpret_cast<ushort4*>(a.dst[k]);
    const int n4 = a.n4[k];
    for (int i = t; i < n4; i += stride) {
      float4 v = src[i];
      ushort4 o;
      o.x = f2b(v.x); o.y = f2b(v.y); o.z = f2b(v.z); o.w = f2b(v.w);
      dst[i] = o;
    }
  }
}

// ---------------- 256x256 tile, BK=64, 8 waves, counted-vmcnt pipeline -----
// (round-3/5 proven schedule.)  MODE 2: G1 fused epilogue — v = acc+bias;
// col<4096 -> xib bf16, col>=4096 -> rsb = silu(v) bf16.
template <int MODE>
__global__ __launch_bounds__(512) void gemm256_bt(
    const unsigned short* __restrict__ A, const unsigned short* __restrict__ B,
    float* __restrict__ Cp, unsigned short* __restrict__ xib,
    unsigned short* __restrict__ rsb, const float* __restrict__ bias,
    int M, int N, int K, int Kslice) {
  __shared__ __align__(16) unsigned short lds[65536];  // [buf:2][A|B][256][64]
  const int tid = threadIdx.x;
  const int l = tid & 63;
  const int w = tid >> 6;       // 0..7
  const int wr = w >> 2;        // 0..1 -> 128-row half
  const int wc = w & 3;         // 0..3 -> 64-col quarter

  // T1: bijective XCD swizzle (nwg % 8 == 0 in all uses)
  const int nwg = gridDim.x * gridDim.y;
  const int q = nwg >> 3;
  int flat = blockIdx.x + gridDim.x * blockIdx.y;
  flat = (flat & 7) * q + (flat >> 3);
  const int bx = flat % gridDim.x;
  const int by = flat / gridDim.x;

  const long brow = (long)bx * 256;
  const long bcol = (long)by * 256;
  const int ks = blockIdx.z;
  const int NT = Kslice >> 6;

  f32x4 acc[8][4] = {};

  const unsigned short* Ab = A + (size_t)brow * K + (size_t)ks * Kslice;
  const unsigned short* Bb = B + (size_t)bcol * K + (size_t)ks * Kslice;
  size_t soff[4];
  int doff[4];
#pragma unroll
  for (int i = 0; i < 4; ++i) {
    int idx = i * 512 + tid;      // 0..2047 -> (row=idx>>3, slot=idx&7)
    int r = idx >> 3, s = idx & 7;
    soff[i] = (size_t)r * K + (size_t)((s ^ (r & 7)) << 3);
    doff[i] = idx * 8;            // ushort offset, 16B per idx
  }

  auto stage = [&](int kt, int buf) {
    const int k0 = kt << 6;
#pragma unroll
    for (int i = 0; i < 4; ++i)
      GLDS16(Ab + soff[i] + k0, &lds[buf * 32768 + doff[i]]);
#pragma unroll
    for (int i = 0; i < 4; ++i)
      GLDS16(Bb + soff[i] + k0, &lds[buf * 32768 + 16384 + doff[i]]);
  };

  const int hi = l >> 4, lo7 = l & 7;
  const int sw0 = ((0 + hi) ^ lo7) << 3;
  const int sw1 = ((4 + hi) ^ lo7) << 3;
  const int rowA = wr * 128 + (l & 15);
  const int colB = wc * 64 + (l & 15);

  stage(0, 0);
  stage(1, 1);

  int buf = 0;
  for (int kt = 0; kt < NT; ++kt) {
    const bool last = (kt == NT - 1);
    if (last) {
      asm volatile("s_waitcnt vmcnt(0)" ::: "memory");
    } else {
      asm volatile("s_waitcnt vmcnt(8)" ::: "memory");
    }
    BARRIER();
    const int bb = buf * 32768;
    bf16x8 a0[8], b0[4];
#pragma unroll
    for (int m = 0; m < 8; ++m)
      a0[m] = *reinterpret_cast<const bf16x8*>(&lds[bb + (rowA + m * 16) * 64 + sw0]);
#pragma unroll
    for (int n = 0; n < 4; ++n)
      b0[n] = *reinterpret_cast<const bf16x8*>(&lds[bb + 16384 + (colB + n * 16) * 64 + sw0]);
    __builtin_amdgcn_s_setprio(1);
#pragma unroll
    for (int m = 0; m < 8; ++m)
#pragma unroll
      for (int n = 0; n < 4; ++n)
        acc[m][n] = __builtin_amdgcn_mfma_f32_16x16x32_bf16(a0[m], b0[n], acc[m][n], 0, 0, 0);
    __builtin_amdgcn_s_setprio(0);
    bf16x8 a1[8], b1[4];
#pragma unroll
    for (int m = 0; m < 8; ++m)
      a1[m] = *reinterpret_cast<const bf16x8*>(&lds[bb + (rowA + m * 16) * 64 + sw1]);
#pragma unroll
    for (int n = 0; n < 4; ++n)
      b1[n] = *reinterpret_cast<const bf16x8*>(&lds[bb + 16384 + (colB + n * 16) * 64 + sw1]);
    asm volatile("s_waitcnt lgkmcnt(0)" ::: "memory");
    __builtin_amdgcn_sched_barrier(0);
    BARRIER();  // all waves done reading this buffer -> safe to overwrite
    if (kt + 2 < NT) stage(kt + 2, buf);
    __builtin_amdgcn_s_setprio(1);
#pragma unroll
    for (int m = 0; m < 8; ++m)
#pragma unroll
      for (int n = 0; n < 4; ++n)
        acc[m][n] = __builtin_amdgcn_mfma_f32_16x16x32_bf16(a1[m], b1[n], acc[m][n], 0, 0, 0);
    __builtin_amdgcn_s_setprio(0);
    buf ^= 1;
  }

  // epilogue: C/D layout col=lane&15, row=(lane>>4)*4+reg
  const long r0 = brow + wr * 128 + (l >> 4) * 4;
  const long c0 = bcol + wc * 64 + (l & 15);
  if (MODE == 1) {
    float* Cb = Cp + (size_t)ks * M * N;
#pragma unroll
    for (int m = 0; m < 8; ++m)
#pragma unroll
      for (int n = 0; n < 4; ++n) {
        long col = c0 + n * 16;
#pragma unroll
        for (int r = 0; r < 4; ++r)
          Cb[(r0 + m * 16 + r) * (long)N + col] = acc[m][n][r];
      }
  } else {
#pragma unroll
    for (int m = 0; m < 8; ++m)
#pragma unroll
      for (int n = 0; n < 4; ++n) {
        long col = c0 + n * 16;
        float bv = bias[col];
        const bool isres = col >= 4096;
        long cc = isres ? col - 4096 : col;
#pragma unroll
        for (int r = 0; r < 4; ++r) {
          float v = acc[m][n][r] + bv;
          if (isres) {
            float s = v * sigmoidf_fast(v);
            rsb[(r0 + m * 16 + r) * 4096 + cc] = f2b(s);
          } else {
            xib[(r0 + m * 16 + r) * 4096 + cc] = f2b(v);
          }
        }
      }
  }
}

// ---------------- 128x128 tile, BK=64, 8 waves, full-K, fused bias ---------
// Same proven counted-vmcnt structure with all dims halved: 4 loads/stage,
// vmcnt(4) steady-state, 16 MFMA/K-tile/wave (acc[4][2]), same XOR swizzle
// (rows are 64 bf16 = 8 x 16B slots).  C = A*B^T + bias, fp32 out.
__global__ __launch_bounds__(512) void gemm128_bt(
    const unsigned short* __restrict__ A, const unsigned short* __restrict__ B,
    float* __restrict__ C, const float* __restrict__ bias,
    int M, int N, int K) {
  __shared__ __align__(16) unsigned short lds[32768];  // [buf:2][A|B][128][64]
  const int tid = threadIdx.x;
  const int l = tid & 63;
  const int w = tid >> 6;       // 0..7
  const int wr = w >> 2;        // 0..1 -> 64-row half
  const int wc = w & 3;         // 0..3 -> 32-col quarter

  // T1: bijective XCD swizzle (256 blocks % 8 == 0)
  const int nwg = gridDim.x * gridDim.y;
  const int q = nwg >> 3;
  int flat = blockIdx.x + gridDim.x * blockIdx.y;
  flat = (flat & 7) * q + (flat >> 3);
  const int bx = flat % gridDim.x;
  const int by = flat / gridDim.x;

  const long brow = (long)bx * 128;
  const long bcol = (long)by * 128;
  const int NT = K >> 6;

  f32x4 acc[4][2] = {};

  const unsigned short* Ab = A + (size_t)brow * K;
  const unsigned short* Bb = B + (size_t)bcol * K;
  size_t soff[2];
  int doff[2];
#pragma unroll
  for (int i = 0; i < 2; ++i) {
    int idx = i * 512 + tid;      // 0..1023 -> (row=idx>>3, slot=idx&7)
    int r = idx >> 3, s = idx & 7;
    soff[i] = (size_t)r * K + (size_t)((s ^ (r & 7)) << 3);
    doff[i] = idx * 8;
  }

  auto stage = [&](int kt, int buf) {
    const int k0 = kt << 6;
#pragma unroll
    for (int i = 0; i < 2; ++i)
      GLDS16(Ab + soff[i] + k0, &lds[buf * 16384 + doff[i]]);
#pragma unroll
    for (int i = 0; i < 2; ++i)
      GLDS16(Bb + soff[i] + k0, &lds[buf * 16384 + 8192 + doff[i]]);
  };

  const int hi = l >> 4, lo7 = l & 7;
  const int sw0 = ((0 + hi) ^ lo7) << 3;
  const int sw1 = ((4 + hi) ^ lo7) << 3;
  const int rowA = wr * 64 + (l & 15);
  const int colB = wc * 32 + (l & 15);

  stage(0, 0);
  stage(1, 1);

  int buf = 0;
  for (int kt = 0; kt < NT; ++kt) {
    const bool last = (kt == NT - 1);
    if (last) {
      asm volatile("s_waitcnt vmcnt(0)" ::: "memory");
    } else {
      asm volatile("s_waitcnt vmcnt(4)" ::: "memory");
    }
    BARRIER();
    const int bb = buf * 16384;
    bf16x8 a0[4], b0[2];
#pragma unroll
    for (int m = 0; m < 4; ++m)
      a0[m] = *reinterpret_cast<const bf16x8*>(&lds[bb + (rowA + m * 16) * 64 + sw0]);
#pragma unroll
    for (int n = 0; n < 2; ++n)
      b0[n] = *reinterpret_cast<const bf16x8*>(&lds[bb + 8192 + (colB + n * 16) * 64 + sw0]);
    __builtin_amdgcn_s_setprio(1);
#pragma unroll
    for (int m = 0; m < 4; ++m)
#pragma unroll
      for (int n = 0; n < 2; ++n)
        acc[m][n] = __builtin_amdgcn_mfma_f32_16x16x32_bf16(a0[m], b0[n], acc[m][n], 0, 0, 0);
    __builtin_amdgcn_s_setprio(0);
    bf16x8 a1[4], b1[2];
#pragma unroll
    for (int m = 0; m < 4; ++m)
      a1[m] = *reinterpret_cast<const bf16x8*>(&lds[bb + (rowA + m * 16) * 64 + sw1]);
#pragma unroll
    for (int n = 0; n < 2; ++n)
      b1[n] = *reinterpret_cast<const bf16x8*>(&lds[bb + 8192 + (colB + n * 16) * 64 + sw1]);
    asm volatile("s_waitcnt lgkmcnt(0)" ::: "memory");
    __builtin_amdgcn_sched_barrier(0);
    BARRIER();  // all waves done reading this buffer -> safe to overwrite
    if (kt + 2 < NT) stage(kt + 2, buf);
    __builtin_amdgcn_s_setprio(1);
#pragma unroll
    for (int m = 0; m < 4; ++m)
#pragma unroll
      for (int n = 0; n < 2; ++n)
        acc[m][n] = __builtin_amdgcn_mfma_f32_16x16x32_bf16(a1[m], b1[n], acc[m][n], 0, 0, 0);
    __builtin_amdgcn_s_setprio(0);
    buf ^= 1;
  }

  const long r0 = brow + wr * 64 + (l >> 4) * 4;
  const long c0 = bcol + wc * 32 + (l & 15);
#pragma unroll
  for (int m = 0; m < 4; ++m) {
#pragma unroll
    for (int n = 0; n < 2; ++n) {
      long col = c0 + n * 16;
      float bv = bias[col];
#pragma unroll
      for (int r = 0; r < 4; ++r)
        C[(r0 + m * 16 + r) * (long)N + col] = acc[m][n][r] + bv;
    }
  }
}

// ---------------- G3: softplus GEMM (m97 structure, 128x128) ----------------
__global__ __launch_bounds__(256) void gemm_bt_sp(
    const unsigned short* __restrict__ A, const unsigned short* __restrict__ B,
    float* __restrict__ C, int M, int N, int K) {
  __shared__ __align__(16) unsigned short lA[128 * 32];
  __shared__ __align__(16) unsigned short lB[128 * 32];
  const int tid = threadIdx.x;
  const int l = tid & 63;
  const int w = tid >> 6;
  const int wr = w >> 1, wc = w & 1;
  const long brow = (long)blockIdx.x * 128;
  const long bcol = (long)blockIdx.y * 128;

  f32x4 acc[4][4] = {};

  const int srow = tid >> 2;
  const int scol = (tid & 3) * 8;

  const unsigned short* Ab = A + (size_t)brow * K;
  const unsigned short* Bb = B + (size_t)bcol * K;

  for (int k0 = 0; k0 < K; k0 += 32) {
#pragma unroll
    for (int j = 0; j < 2; ++j) {
      GLDS16(Ab + (size_t)(j * 64 + srow) * K + k0 + scol, &lA[j * 2048 + tid * 8]);
      GLDS16(Bb + (size_t)(j * 64 + srow) * K + k0 + scol, &lB[j * 2048 + tid * 8]);
    }
    __syncthreads();
    bf16x8 af[4], bfr[4];
#pragma unroll
    for (int mt = 0; mt < 4; ++mt)
      af[mt] = *reinterpret_cast<const bf16x8*>(
          &lA[(wr * 64 + mt * 16 + (l & 15)) * 32 + (l >> 4) * 8]);
#pragma unroll
    for (int nt = 0; nt < 4; ++nt)
      bfr[nt] = *reinterpret_cast<const bf16x8*>(
          &lB[(wc * 64 + nt * 16 + (l & 15)) * 32 + (l >> 4) * 8]);
#pragma unroll
    for (int mt = 0; mt < 4; ++mt)
#pragma unroll
      for (int nt = 0; nt < 4; ++nt)
        acc[mt][nt] = __builtin_amdgcn_mfma_f32_16x16x32_bf16(
            af[mt], bfr[nt], acc[mt][nt], 0, 0, 0);
    __syncthreads();
  }

  const long r0 = brow + wr * 64 + ((l >> 4) * 4);
  const long c0 = bcol + wc * 64 + (l & 15);
#pragma unroll
  for (int mt = 0; mt < 4; ++mt) {
#pragma unroll
    for (int nt = 0; nt < 4; ++nt) {
      long col = c0 + nt * 16;
#pragma unroll
      for (int r = 0; r < 4; ++r) {
        long row = r0 + mt * 16 + r;
        float v = acc[mt][nt][r];
        v = (v > 20.0f) ? v : log1pf(__expf(v));
        C[row * (long)N + col] = v;
      }
    }
  }
}

// ---------------- depthwise causal conv1d (k=4) + SiLU, bf16 in/out --------
__global__ __launch_bounds__(256) void conv_silu_k(
    const unsigned short* __restrict__ xib, const float* __restrict__ cw,
    const float* __restrict__ cb, unsigned short* __restrict__ xcb) {
  const int d = blockIdx.x * 256 + threadIdx.x;  // 0..4095
  const int t0 = blockIdx.y * 128;
  const float4 wv = *reinterpret_cast<const float4*>(cw + (size_t)d * 4);
  const float bv = cb[d];
  float xm3 = (t0 >= 3) ? b2f(xib[(size_t)(t0 - 3) * 4096 + d]) : 0.0f;
  float xm2 = (t0 >= 2) ? b2f(xib[(size_t)(t0 - 2) * 4096 + d]) : 0.0f;
  float xm1 = (t0 >= 1) ? b2f(xib[(size_t)(t0 - 1) * 4096 + d]) : 0.0f;
  for (int tt = 0; tt < 128; ++tt) {
    const size_t t = (size_t)t0 + tt;
    float xt = b2f(xib[t * 4096 + d]);
    float a = bv + wv.x * xm3 + wv.y * xm2 + wv.z * xm1 + wv.w * xt;
    float s = a * sigmoidf_fast(a);
    xcb[t * 4096 + d] = f2b(s);
    xm3 = xm2; xm2 = xm1; xm1 = xt;
  }
}

// ---------------- G2: dbc partials, K-split x8 ----------------
__global__ __launch_bounds__(256) void gemm_dbc(
    const unsigned short* __restrict__ A, const unsigned short* __restrict__ B,
    float* __restrict__ part) {
  __shared__ __align__(16) unsigned short lA[64 * 32];
  __shared__ __align__(16) unsigned short lB[160 * 32];
  const int tid = threadIdx.x;
  const int l = tid & 63, w = tid >> 6;
  const int brow = blockIdx.x * 64;
  const int ks = blockIdx.y;
  const int K = 4096;
  f32x4 acc[10] = {};
  const int srow = tid >> 2, scol = (tid & 3) * 8;
  for (int k0 = ks * 512; k0 < ks * 512 + 512; k0 += 32) {
    GLDS16(A + (size_t)(brow + srow) * K + k0 + scol, &lA[tid * 8]);
#pragma unroll
    for (int j = 0; j < 3; ++j) {
      int li = j * 256 + tid;
      if (li < 640) {
        GLDS16(B + (size_t)(li >> 2) * K + k0 + (li & 3) * 8, &lB[li * 8]);
      }
    }
    __syncthreads();
    bf16x8 af = *reinterpret_cast<const bf16x8*>(
        &lA[(w * 16 + (l & 15)) * 32 + (l >> 4) * 8]);
#pragma unroll
    for (int nt = 0; nt < 10; ++nt) {
      bf16x8 bfr = *reinterpret_cast<const bf16x8*>(
          &lB[(nt * 16 + (l & 15)) * 32 + (l >> 4) * 8]);
      acc[nt] = __builtin_amdgcn_mfma_f32_16x16x32_bf16(af, bfr, acc[nt], 0, 0, 0);
    }
    __syncthreads();
  }
  const int r0 = brow + w * 16 + (l >> 4) * 4;
  const int c = l & 15;
#pragma unroll
  for (int nt = 0; nt < 10; ++nt)
#pragma unroll
    for (int r = 0; r < 4; ++r)
      part[((size_t)ks * 2048 + r0 + r) * 160 + nt * 16 + c] = acc[nt][r];
}

__global__ __launch_bounds__(256) void reduce_dbc(
    const float* __restrict__ part, unsigned short* __restrict__ drb,
    float* __restrict__ bc) {
  int idx = blockIdx.x * 256 + threadIdx.x;
  float s = 0.0f;
#pragma unroll
  for (int k = 0; k < 8; ++k) s += part[(size_t)k * 2048 * 160 + idx];
  int row = idx / 160, col = idx - row * 160;
  if (col < 128) drb[row * 128 + col] = f2b(s);
  else bc[row * 32 + (col - 128)] = s;
}

// ---------------- chunked selective scan (u from bf16) ----------------
__global__ __launch_bounds__(256) void scan_passA(
    const float* __restrict__ delta, const unsigned short* __restrict__ xcb,
    const float* __restrict__ bc, const float* __restrict__ alog,
    float* __restrict__ P, float* __restrict__ S) {
  __shared__ float lbc[1024];
  const int d = blockIdx.x * 256 + threadIdx.x;
  const int c = blockIdx.y;
  const int t0 = c * 32;
#pragma unroll
  for (int j = 0; j < 4; ++j) {
    int idx = j * 256 + threadIdx.x;
    lbc[idx] = bc[(size_t)t0 * 32 + idx];
  }
  __syncthreads();
  float a[16], h[16], p[16];
#pragma unroll
  for (int s = 0; s < 16; ++s) {
    a[s] = -__expf(alog[(size_t)d * 16 + s]);
    h[s] = 0.0f;
    p[s] = 1.0f;
  }
  for (int tt = 0; tt < 32; ++tt) {
    float dt = delta[(size_t)(t0 + tt) * 4096 + d];
    float u = b2f(xcb[(size_t)(t0 + tt) * 4096 + d]);
    float du = dt * u;
#pragma unroll
    for (int s = 0; s < 16; ++s) {
      float e = __expf(dt * a[s]);
      h[s] = e * h[s] + du * lbc[tt * 32 + s];
      p[s] *= e;
    }
  }
  size_t o = ((size_t)c * 4096 + d) * 16;
#pragma unroll
  for (int s = 0; s < 16; s += 4) {
    *reinterpret_cast<float4*>(&P[o + s]) = make_float4(p[s], p[s + 1], p[s + 2], p[s + 3]);
    *reinterpret_cast<float4*>(&S[o + s]) = make_float4(h[s], h[s + 1], h[s + 2], h[s + 3]);
  }
}

__global__ __launch_bounds__(256) void scan_passB(
    float* __restrict__ P, const float* __restrict__ S) {
  const int idx = blockIdx.x * 256 + threadIdx.x;
  float h = 0.0f;
  for (int c = 0; c < 64; ++c) {
    size_t o = (size_t)c * 65536 + idx;
    float p = P[o], sv = S[o];
    P[o] = h;
    h = p * h + sv;
  }
}

__global__ __launch_bounds__(256) void scan_passC(
    const float* __restrict__ delta, const unsigned short* __restrict__ xcb,
    const float* __restrict__ bc, const float* __restrict__ alog,
    const float* __restrict__ hst, const float* __restrict__ Dp,
    const unsigned short* __restrict__ rsb, unsigned short* __restrict__ yb) {
  __shared__ float lbc[1024];
  const int d = blockIdx.x * 256 + threadIdx.x;
  const int c = blockIdx.y;
  const int t0 = c * 32;
#pragma unroll
  for (int j = 0; j < 4; ++j) {
    int idx = j * 256 + threadIdx.x;
    lbc[idx] = bc[(size_t)t0 * 32 + idx];
  }
  __syncthreads();
  float a[16], h[16];
  size_t o = ((size_t)c * 4096 + d) * 16;
#pragma unroll
  for (int s = 0; s < 16; ++s) {
    a[s] = -__expf(alog[(size_t)d * 16 + s]);
    h[s] = hst[o + s];
  }
  const float Dv = Dp[d];
  for (int tt = 0; tt < 32; ++tt) {
    float dt = delta[(size_t)(t0 + tt) * 4096 + d];
    float u = b2f(xcb[(size_t)(t0 + tt) * 4096 + d]);
    float du = dt * u;
    float y = 0.0f;
#pragma unroll
    for (int s = 0; s < 16; ++s) {
      float e = __expf(dt * a[s]);
      h[s] = e * h[s] + du * lbc[tt * 32 + s];
      y += h[s] * lbc[tt * 32 + 16 + s];
    }
    float rs = b2f(rsb[(size_t)(t0 + tt) * 4096 + d]);  // silu(res), precomputed
    float v = (y + u * Dv) * rs;
    yb[(size_t)(t0 + tt) * 4096 + d] = f2b(v);
  }
}

// ---------------------------------------------------------------------------
extern "C" void kernel_launch(void* const* d_in, const int* in_sizes, int n_in,
                              void* d_out, int out_size, void* d_ws, size_t ws_size,
                              hipStream_t stream) {
  const float* x    = (const float*)d_in[0];
  const float* w1   = (const float*)d_in[1];
  const float* b1   = (const float*)d_in[2];
  const float* cw   = (const float*)d_in[3];
  const float* cb   = (const float*)d_in[4];
  const float* w2   = (const float*)d_in[5];
  const float* w3   = (const float*)d_in[6];
  const float* alog = (const float*)d_in[7];
  const float* Dp   = (const float*)d_in[8];
  const float* w4   = (const float*)d_in[9];
  const float* b4   = (const float*)d_in[10];
  float* out = (float*)d_out;

  char* ws = (char*)d_ws;
  size_t off = 0;
  auto alloc = [&](size_t b) {
    size_t o = off;
    off += (b + 255) & ~(size_t)255;
    return o;
  };
  unsigned short* w1b = (unsigned short*)(ws + alloc(2ull * 8192 * 2048));
  unsigned short* xb  = (unsigned short*)(ws + alloc(2ull * 2048 * 2048));
  unsigned short* w2b = (unsigned short*)(ws + alloc(2ull * 160 * 4096));
  unsigned short* w3b = (unsigned short*)(ws + alloc(2ull * 4096 * 128));
  unsigned short* w4b = (unsigned short*)(ws + alloc(2ull * 2048 * 4096));
  unsigned short* xib = (unsigned short*)(ws + alloc(2ull * 2048 * 4096));
  unsigned short* rsb = (unsigned short*)(ws + alloc(2ull * 2048 * 4096));
  unsigned short* xcb = (unsigned short*)(ws + alloc(2ull * 2048 * 4096));
  unsigned short* drb = (unsigned short*)(ws + alloc(2ull * 2048 * 128));
  float* bcb  = (float*)(ws + alloc(4ull * 2048 * 32));
  float* delta = (float*)(ws + alloc(4ull * 2048 * 4096));
  float* P = (float*)(ws + alloc(4ull * 64 * 4096 * 16));
  float* S = (float*)(ws + alloc(4ull * 64 * 4096 * 16));
  float* part  = delta;                 // G2 partials (10.5MB), consumed pre-G3
  unsigned short* yb = xib;             // xib dead after conv

  if (ws_size < off) return;

  CastArgs ca;
  ca.src[0] = w1; ca.dst[0] = w1b; ca.n4[0] = 8192 * 2048 / 4;
  ca.src[1] = x;  ca.dst[1] = xb;  ca.n4[1] = 2048 * 2048 / 4;
  ca.src[2] = w2; ca.dst[2] = w2b; ca.n4[2] = 160 * 4096 / 4;
  ca.src[3] = w3; ca.dst[3] = w3b; ca.n4[3] = 4096 * 128 / 4;
  ca.src[4] = w4; ca.dst[4] = w4b; ca.n4[4] = 2048 * 4096 / 4;
  cast_multi<<<2048, 256, 0, stream>>>(ca);

  // G1: (M=2048, N=8192, K=2048) -> xib (bf16), rsb = silu(res) (bf16)
  gemm256_bt<2><<<dim3(8, 32, 1), 512, 0, stream>>>(
      xb, w1b, nullptr, xib, rsb, b1, 2048, 8192, 2048, 2048);
  // conv + silu (bf16 in/out)
  conv_silu_k<<<dim3(16, 16), 256, 0, stream>>>(xib, cw, cb, xcb);
  // G2 + reduce
  gemm_dbc<<<dim3(32, 8), 256, 0, stream>>>(xcb, w2b, part);
  reduce_dbc<<<1280, 256, 0, stream>>>(part, drb, bcb);
  // G3: delta = softplus(dr @ delta_w^T)
  gemm_bt_sp<<<dim3(16, 32), 256, 0, stream>>>(drb, w3b, delta, 2048, 4096, 128);
  // scan
  scan_passA<<<dim3(16, 64), 256, 0, stream>>>(delta, xcb, bcb, alog, P, S);
  scan_passB<<<256, 256, 0, stream>>>(P, S);
  scan_passC<<<dim3(16, 64), 256, 0, stream>>>(delta, xcb, bcb, alog, P, Dp, rsb, yb);
  // G4: out = y @ out_w^T + b4   (M=2048, N=2048, K=4096) — full-K 128sq
  gemm128_bt<<<dim3(16, 16), 512, 0, stream>>>(yb, w4b, out, b4, 2048, 2048, 4096);
}